// Round 5
// baseline (113.243 us; speedup 1.0000x reference)
//
#include <hip/hip_runtime.h>

typedef short s16x8 __attribute__((ext_vector_type(8)));
typedef float f32x4 __attribute__((ext_vector_type(4)));
typedef float f32x16 __attribute__((ext_vector_type(16)));
typedef unsigned int u32x4 __attribute__((ext_vector_type(4)));

#define MFMA16(a, b, c) __builtin_amdgcn_mfma_f32_16x16x32_bf16(a, b, c, 0, 0, 0)
#define MFMA32(a, b, c) __builtin_amdgcn_mfma_f32_32x32x16_bf16(a, b, c, 0, 0, 0)

__device__ __forceinline__ unsigned short f2bf(float f) {
  unsigned int u = __builtin_bit_cast(unsigned int, f);
  u += 0x7FFFu + ((u >> 16) & 1u);
  return (unsigned short)(u >> 16);
}

__device__ __forceinline__ unsigned cvtpk(float lo, float hi) {
  unsigned r;
  asm("v_cvt_pk_bf16_f32 %0, %1, %2" : "=v"(r) : "v"(lo), "v"(hi));
  return r;
}

// vdst' = (vdst.lo, vsrc.lo); vsrc' = (vdst.hi, vsrc.hi)
__device__ __forceinline__ void plswap(unsigned& a, unsigned& b) {
  asm("v_permlane32_swap_b32 %0, %1" : "+v"(a), "+v"(b));
}

// ---------- kernel 1: W [1024][64] fp32 -> Wt [3][64][1024] bf16 ----------
__global__ __launch_bounds__(256) void wt_kernel(const float* __restrict__ Wq,
                                                 const float* __restrict__ Wk,
                                                 const float* __restrict__ Wv,
                                                 unsigned short* __restrict__ Wt) {
  int i = blockIdx.x * 256 + threadIdx.x;  // 3*64*1024 = 196608 total
  int m = i >> 16;
  int rem = i & 65535;
  int h = rem >> 10;
  int c = rem & 1023;
  const float* W = (m == 0) ? Wq : (m == 1) ? Wk : Wv;
  Wt[i] = f2bf(W[c * 64 + h]);
}

// ---------- kernel 2: projection GEMM, single-drain staging ----------
// 1024 blocks x 256 thr (4 waves). Tile: 16 rows x 192 cols, K=1024 whole.
// Stage the ENTIRE 16x1024 fp32 x-tile into 64 KiB LDS with 16 back-to-back
// global_load_lds (all in flight together -> latency paid once), ONE
// __syncthreads (the only vmcnt(0) drain), then a barrier-free compute loop.
// XOR-swizzle in 16B chunks: linear LDS dest + inverse-swizzled global source
// + swizzled ds_read (rule #21 both-sides). Wave wv owns cols [48wv,48wv+48).
__global__ __launch_bounds__(256) void proj_kernel(const float* __restrict__ x,
                                                   const unsigned short* __restrict__ Wt,
                                                   unsigned short* __restrict__ qm,
                                                   unsigned short* __restrict__ km,
                                                   unsigned short* __restrict__ vt) {
  __shared__ float xb[16][1024];  // 64 KiB -> 2 blocks/CU

  int tid = threadIdx.x;
  int lane = tid & 63, wv = tid >> 6;
  int c = lane & 15, g = lane >> 4;
  int row0 = blockIdx.x * 16;
  int b = row0 >> 12;

  // staging: thread tid fills 16B chunk #tid of each K-step slab (dest slot
  // cs of row srow); source chunk is cs ^ (srow&7) so slot s holds logical
  // chunk s ^ (row&7).
  int srow = tid >> 4;
  int scs = tid & 15;
  int schunk = scs ^ (srow & 7);
  const float* sbase = x + (size_t)(row0 + srow) * 1024 + schunk * 4;

#pragma unroll
  for (int t = 0; t < 16; ++t) {
    __builtin_amdgcn_global_load_lds(
        (const __attribute__((address_space(1))) unsigned int*)(sbase + t * 64),
        (__attribute__((address_space(3))) unsigned int*)(&xb[t][wv * 256]), 16, 0, 0);
  }

  f32x4 acc[3];
  acc[0] = (f32x4){0.f, 0.f, 0.f, 0.f};
  acc[1] = acc[0];
  acc[2] = acc[0];

  __syncthreads();  // the single vmcnt(0) drain

#pragma unroll 4
  for (int t = 0; t < 16; ++t) {
    const float* xs = xb[t];
    int k0 = t * 64;
#pragma unroll
    for (int kk = 0; kk < 2; ++kk) {
      // A fragment: row c, floats [32kk+8g, +8) -> swizzled 16B chunks
      int s0 = (8 * kk + 2 * g) ^ (c & 7);
      int s1 = (8 * kk + 2 * g + 1) ^ (c & 7);
      f32x4 a0 = *(const f32x4*)(xs + c * 64 + s0 * 4);
      f32x4 a1 = *(const f32x4*)(xs + c * 64 + s1 * 4);
      s16x8 af;
      unsigned* au = (unsigned*)&af;
      au[0] = cvtpk(a0[0], a0[1]);
      au[1] = cvtpk(a0[2], a0[3]);
      au[2] = cvtpk(a1[0], a1[1]);
      au[3] = cvtpk(a1[2], a1[3]);
#pragma unroll
      for (int n = 0; n < 3; ++n) {
        int gcolc = 48 * wv + 16 * n + c;
        s16x8 bf = *(const s16x8*)(Wt + (size_t)gcolc * 1024 + k0 + 32 * kk + 8 * g);
        acc[n] = MFMA16(af, bf, acc[n]);
      }
    }
  }

#pragma unroll
  for (int n = 0; n < 3; ++n) {
    int base = 48 * wv + 16 * n;  // 16-aligned, never straddles a 64-boundary
    int m = base >> 6;
    int gcolc = base + c;
    int h = gcolc & 63;
#pragma unroll
    for (int r = 0; r < 4; ++r) {
      unsigned short hv = f2bf(acc[n][r]);
      int grow = row0 + 4 * g + r;
      if (m == 0) qm[(size_t)grow * 64 + h] = hv;
      else if (m == 1) km[(size_t)grow * 64 + h] = hv;
      else vt[((size_t)b * 64 + h) * 4096 + (grow & 4095)] = hv;
    }
  }
}

// ---------- kernel 3: flash attention, swapped-QK^T 32x32 structure ----------
__global__ __launch_bounds__(512) void attn_kernel(const unsigned short* __restrict__ qm,
                                                   const unsigned short* __restrict__ km,
                                                   const unsigned short* __restrict__ vt,
                                                   float* __restrict__ out) {
  __shared__ float Olds[4][32][64];  // 32 KiB, used in 2 phases (waves 0-3, 4-7)
  __shared__ float mlds[8][32];
  __shared__ float llds[8][32];
  __shared__ float flds[8][32];

  int tid = threadIdx.x;
  int lane = tid & 63, wv = tid >> 6;
  int ln = lane & 31, hi = lane >> 5;
  int bid = blockIdx.x;
  int b = bid & 3;
  int j = 127 - (bid >> 2);  // big Q-tiles dispatched first
  int q0 = j * 32;
  const float SC = 0.1803368801111204f;  // (1/sqrt(64)) * log2(e)

  const unsigned short* qb = qm + ((size_t)b * 4096 + q0 + ln) * 64 + 8 * hi;
  s16x8 qf0 = *(const s16x8*)(qb);
  s16x8 qf1 = *(const s16x8*)(qb + 16);
  s16x8 qf2 = *(const s16x8*)(qb + 32);
  s16x8 qf3 = *(const s16x8*)(qb + 48);

  const unsigned short* kbb = km + (size_t)b * 4096 * 64 + (size_t)ln * 64 + 8 * hi;
  const unsigned short* vbb = vt + (size_t)b * 64 * 4096 + (size_t)ln * 4096 + 8 * hi;

  f32x16 of0 = {0.f, 0.f, 0.f, 0.f, 0.f, 0.f, 0.f, 0.f,
                0.f, 0.f, 0.f, 0.f, 0.f, 0.f, 0.f, 0.f};
  f32x16 of1 = of0;
  float mrow = -1e30f;
  float l = 0.f;

  auto process = [&](int kv0, bool diag) {
    const unsigned short* kp = kbb + (size_t)kv0 * 64;
    s16x8 kf0 = *(const s16x8*)(kp);
    s16x8 kf1 = *(const s16x8*)(kp + 16);
    s16x8 kf2 = *(const s16x8*)(kp + 32);
    s16x8 kf3 = *(const s16x8*)(kp + 48);
    f32x16 s = {0.f, 0.f, 0.f, 0.f, 0.f, 0.f, 0.f, 0.f,
                0.f, 0.f, 0.f, 0.f, 0.f, 0.f, 0.f, 0.f};
    __builtin_amdgcn_s_setprio(1);
    s = MFMA32(kf0, qf0, s);
    s = MFMA32(kf1, qf1, s);
    s = MFMA32(kf2, qf2, s);
    s = MFMA32(kf3, qf3, s);
    __builtin_amdgcn_s_setprio(0);

    float p[16];
#pragma unroll
    for (int r = 0; r < 16; ++r) p[r] = s[r] * SC;
    if (diag) {
#pragma unroll
      for (int r = 0; r < 16; ++r) {
        int kvr = (r & 3) + 8 * (r >> 2) + 4 * hi;
        if (kvr > ln) p[r] = -1e30f;
      }
    }
    float tmax = fmaxf(p[0], p[1]);
#pragma unroll
    for (int r = 2; r < 16; ++r) tmax = fmaxf(tmax, p[r]);
    tmax = fmaxf(tmax, __shfl_xor(tmax, 32));
    if (!__all(tmax <= mrow + 8.0f)) {
      float nm = fmaxf(mrow, tmax);
      float al = __builtin_amdgcn_exp2f(mrow - nm);
      mrow = nm;
      l *= al;
#pragma unroll
      for (int r = 0; r < 16; ++r) { of0[r] *= al; of1[r] *= al; }
    }
    float lp = 0.f;
#pragma unroll
    for (int r = 0; r < 16; ++r) {
      p[r] = __builtin_amdgcn_exp2f(p[r] - mrow);
      lp += p[r];
    }
    lp += __shfl_xor(lp, 32);
    l += lp;

    u32x4 w0, w1;
    {
      unsigned x0 = cvtpk(p[0], p[1]), y0 = cvtpk(p[4], p[5]);
      plswap(x0, y0);
      unsigned x1 = cvtpk(p[2], p[3]), y1 = cvtpk(p[6], p[7]);
      plswap(x1, y1);
      w0[0] = x0; w0[1] = x1; w0[2] = y0; w0[3] = y1;
      unsigned x2 = cvtpk(p[8], p[9]), y2 = cvtpk(p[12], p[13]);
      plswap(x2, y2);
      unsigned x3 = cvtpk(p[10], p[11]), y3 = cvtpk(p[14], p[15]);
      plswap(x3, y3);
      w1[0] = x2; w1[1] = x3; w1[2] = y2; w1[3] = y3;
    }
    s16x8 pa0 = __builtin_bit_cast(s16x8, w0);
    s16x8 pa1 = __builtin_bit_cast(s16x8, w1);

    const unsigned short* vp = vbb + kv0;
    s16x8 vf00 = *(const s16x8*)(vp);
    s16x8 vf01 = *(const s16x8*)(vp + 16);
    s16x8 vf10 = *(const s16x8*)(vp + 32 * 4096);
    s16x8 vf11 = *(const s16x8*)(vp + 32 * 4096 + 16);
    __builtin_amdgcn_s_setprio(1);
    of0 = MFMA32(pa0, vf00, of0);
    of0 = MFMA32(pa1, vf01, of0);
    of1 = MFMA32(pa0, vf10, of1);
    of1 = MFMA32(pa1, vf11, of1);
    __builtin_amdgcn_s_setprio(0);
  };

  for (int t = wv; t < j; t += 8) process(t * 32, false);
  if (wv == (j & 7)) process(q0, true);

  if (hi == 0) {
    mlds[wv][ln] = mrow;
    llds[wv][ln] = l;
  }
  __syncthreads();

  if (tid < 32) {
    int row = tid;
    float M = mlds[0][row];
#pragma unroll
    for (int w = 1; w < 8; ++w) M = fmaxf(M, mlds[w][row]);
    float L = 0.f, f[8];
#pragma unroll
    for (int w = 0; w < 8; ++w) {
      f[w] = __builtin_amdgcn_exp2f(mlds[w][row] - M);
      L += llds[w][row] * f[w];
    }
    float rL = 1.0f / L;
#pragma unroll
    for (int w = 0; w < 8; ++w) flds[w][row] = f[w] * rL;
  }

  if (wv < 4) {
#pragma unroll
    for (int r = 0; r < 16; ++r) {
      int qr = (r & 3) + 8 * (r >> 2) + 4 * hi;
      Olds[wv][qr][ln] = of0[r];
      Olds[wv][qr][32 + ln] = of1[r];
    }
  }
  __syncthreads();

  float accv[4];
#pragma unroll
  for (int ii = 0; ii < 4; ++ii) {
    int idx = ii * 512 + tid;
    int row = idx >> 6, d = idx & 63;
    float a = 0.f;
#pragma unroll
    for (int w = 0; w < 4; ++w) a += Olds[w][row][d] * flds[w][row];
    accv[ii] = a;
  }
  __syncthreads();

  if (wv >= 4) {
#pragma unroll
    for (int r = 0; r < 16; ++r) {
      int qr = (r & 3) + 8 * (r >> 2) + 4 * hi;
      Olds[wv - 4][qr][ln] = of0[r];
      Olds[wv - 4][qr][32 + ln] = of1[r];
    }
  }
  __syncthreads();

#pragma unroll
  for (int ii = 0; ii < 4; ++ii) {
    int idx = ii * 512 + tid;
    int row = idx >> 6, d = idx & 63;
    float a = accv[ii];
#pragma unroll
    for (int w = 0; w < 4; ++w) a += Olds[w][row][d] * flds[w + 4][row];
    out[((size_t)b * 4096 + q0 + row) * 64 + d] = a;
  }
}

extern "C" void kernel_launch(void* const* d_in, const int* in_sizes, int n_in,
                              void* d_out, int out_size, void* d_ws, size_t ws_size,
                              hipStream_t stream) {
  const float* x = (const float*)d_in[0];
  const float* Wq = (const float*)d_in[1];
  const float* Wk = (const float*)d_in[2];
  const float* Wv = (const float*)d_in[3];
  float* out = (float*)d_out;

  char* ws = (char*)d_ws;
  unsigned short* Wt = (unsigned short*)ws;                  // 384 KiB
  unsigned short* qm = (unsigned short*)(ws + 0x60000);      // 2 MiB
  unsigned short* km = qm + (size_t)16384 * 64;              // 2 MiB
  unsigned short* vt = km + (size_t)16384 * 64;              // [4][64][4096] bf16

  wt_kernel<<<dim3(768), dim3(256), 0, stream>>>(Wq, Wk, Wv, Wt);
  proj_kernel<<<dim3(1024), dim3(256), 0, stream>>>(x, Wt, qm, km, vt);
  attn_kernel<<<dim3(512), dim3(512), 0, stream>>>(qm, km, vt, out);
}

// Round 6
// 75.724 us; speedup vs baseline: 1.4955x; 1.4955x over previous
//
#include <hip/hip_runtime.h>

typedef short s16x8 __attribute__((ext_vector_type(8)));
typedef float f32x4 __attribute__((ext_vector_type(4)));
typedef float f32x16 __attribute__((ext_vector_type(16)));
typedef unsigned int u32x4 __attribute__((ext_vector_type(4)));

#define MFMA16(a, b, c) __builtin_amdgcn_mfma_f32_16x16x32_bf16(a, b, c, 0, 0, 0)
#define MFMA32(a, b, c) __builtin_amdgcn_mfma_f32_32x32x16_bf16(a, b, c, 0, 0, 0)

__device__ __forceinline__ unsigned short f2bf(float f) {
  unsigned int u = __builtin_bit_cast(unsigned int, f);
  u += 0x7FFFu + ((u >> 16) & 1u);
  return (unsigned short)(u >> 16);
}

__device__ __forceinline__ unsigned cvtpk(float lo, float hi) {
  unsigned r;
  asm("v_cvt_pk_bf16_f32 %0, %1, %2" : "=v"(r) : "v"(lo), "v"(hi));
  return r;
}

// vdst' = (vdst.lo, vsrc.lo); vsrc' = (vdst.hi, vsrc.hi)
__device__ __forceinline__ void plswap(unsigned& a, unsigned& b) {
  asm("v_permlane32_swap_b32 %0, %1" : "+v"(a), "+v"(b));
}

// ---------- kernel 1: W [1024][64] fp32 -> Wt [3][64][1024] bf16 ----------
// LDS-transpose version: coalesced reads (float4 along W rows), coalesced-ish
// 8B writes. 48 blocks x 256 thr, 64x64 tile each.
__global__ __launch_bounds__(256) void wt_kernel(const float* __restrict__ Wq,
                                                 const float* __restrict__ Wk,
                                                 const float* __restrict__ Wv,
                                                 unsigned short* __restrict__ Wt) {
  __shared__ float w[64][65];
  int blk = blockIdx.x;  // 48 = 3 matrices x 16 column-tiles
  int m = blk >> 4;
  int c0 = (blk & 15) * 64;
  const float* W = (m == 0) ? Wq : (m == 1) ? Wk : Wv;
  int tid = threadIdx.x;
#pragma unroll
  for (int k = 0; k < 4; ++k) {
    int id = tid + k * 256;  // 0..1023 = 64 c-rows x 16 float4 chunks
    int crow = id >> 4, ch = id & 15;
    float4 v = *(const float4*)(W + (size_t)(c0 + crow) * 64 + ch * 4);
    w[crow][ch * 4 + 0] = v.x;
    w[crow][ch * 4 + 1] = v.y;
    w[crow][ch * 4 + 2] = v.z;
    w[crow][ch * 4 + 3] = v.w;
  }
  __syncthreads();
#pragma unroll
  for (int k = 0; k < 4; ++k) {
    int id = tid + k * 256;  // 64 h-rows x 16 4-col chunks
    int h = id >> 4, j = id & 15;
    ushort4 o;
    o.x = f2bf(w[4 * j + 0][h]);
    o.y = f2bf(w[4 * j + 1][h]);
    o.z = f2bf(w[4 * j + 2][h]);
    o.w = f2bf(w[4 * j + 3][h]);
    *(ushort4*)(Wt + (size_t)(m * 64 + h) * 1024 + c0 + 4 * j) = o;
  }
}

// ---------- kernel 2: projection GEMM, fully LDS-staged A AND B ----------
// 512 blocks x 512 thr (8 waves, 2M x 4N). Tile: 32 rows x 192 cols, BK=64,
// 16 K-steps, 2-phase double-buffer (stage t+1 before compute t, one barrier).
// BOTH operands staged via global_load_lds with rule-21 both-sides XOR swizzle
// (linear LDS dest + inverse-swizzled per-lane global source + swizzled read).
// This removes the per-wave 16-line Wt global scatter that capped R0-R4.
__global__ __launch_bounds__(512) void proj_kernel(const float* __restrict__ x,
                                                   const unsigned short* __restrict__ Wt,
                                                   unsigned short* __restrict__ qm,
                                                   unsigned short* __restrict__ km,
                                                   unsigned short* __restrict__ vt) {
  __shared__ float xb[2][32 * 64];           // 2 x 8 KiB  (32 rows x 64 fp32)
  __shared__ unsigned short bb[2][192 * 64]; // 2 x 24 KiB (192 rows x 64 bf16)

  int tid = threadIdx.x;
  int lane = tid & 63, wv = tid >> 6;
  int c = lane & 15, g = lane >> 4;
  int wr = wv & 1, wc = wv >> 1;
  int row0 = blockIdx.x * 32;
  int b = blockIdx.x >> 7;

  // x staging: chunk d = tid (32 rows x 16 slots); slot s of row r holds
  // source 16B-chunk s ^ (r&7).
  const float* xsrc =
      x + (size_t)(row0 + (tid >> 4)) * 1024 + ((tid & 15) ^ ((tid >> 4) & 7)) * 4;
  // B staging: chunks d = tid + 512e (192 rows x 8 slots); slot s of row hr
  // holds source chunk s ^ (hr&7).
  const unsigned short* bsrc0;
  const unsigned short* bsrc1;
  const unsigned short* bsrc2;
  {
    int d0 = tid, d1 = tid + 512, d2 = tid + 1024;
    bsrc0 = Wt + (size_t)(d0 >> 3) * 1024 + ((d0 & 7) ^ ((d0 >> 3) & 7)) * 8;
    bsrc1 = Wt + (size_t)(d1 >> 3) * 1024 + ((d1 & 7) ^ ((d1 >> 3) & 7)) * 8;
    bsrc2 = Wt + (size_t)(d2 >> 3) * 1024 + ((d2 & 7) ^ ((d2 >> 3) & 7)) * 8;
  }

#define STAGE(buf, t)                                                                 \
  do {                                                                                \
    __builtin_amdgcn_global_load_lds(                                                 \
        (const __attribute__((address_space(1))) unsigned int*)(xsrc + (t) * 64),     \
        (__attribute__((address_space(3))) unsigned int*)(&xb[buf][wv * 256]), 16, 0, 0); \
    __builtin_amdgcn_global_load_lds(                                                 \
        (const __attribute__((address_space(1))) unsigned int*)(bsrc0 + (t) * 64),    \
        (__attribute__((address_space(3))) unsigned int*)(&bb[buf][wv * 512]), 16, 0, 0); \
    __builtin_amdgcn_global_load_lds(                                                 \
        (const __attribute__((address_space(1))) unsigned int*)(bsrc1 + (t) * 64),    \
        (__attribute__((address_space(3))) unsigned int*)(&bb[buf][wv * 512 + 4096]), 16, 0, 0); \
    __builtin_amdgcn_global_load_lds(                                                 \
        (const __attribute__((address_space(1))) unsigned int*)(bsrc2 + (t) * 64),    \
        (__attribute__((address_space(3))) unsigned int*)(&bb[buf][wv * 512 + 8192]), 16, 0, 0); \
  } while (0)

  f32x4 acc[3];
  acc[0] = (f32x4){0.f, 0.f, 0.f, 0.f};
  acc[1] = acc[0];
  acc[2] = acc[0];

  STAGE(0, 0);
  __syncthreads();

  int arow = 16 * wr + c;
  for (int t = 0; t < 16; ++t) {
    int buf = t & 1;
    if (t < 15) STAGE(buf ^ 1, t + 1);
    const float* xs = xb[buf];
    const unsigned short* bs = bb[buf];
#pragma unroll
    for (int kk = 0; kk < 2; ++kk) {
      int s0 = (8 * kk + 2 * g) ^ (c & 7);
      f32x4 a0 = *(const f32x4*)(xs + arow * 64 + s0 * 4);
      f32x4 a1 = *(const f32x4*)(xs + arow * 64 + (s0 ^ 1) * 4);
      s16x8 af;
      unsigned* au = (unsigned*)&af;
      au[0] = cvtpk(a0[0], a0[1]);
      au[1] = cvtpk(a0[2], a0[3]);
      au[2] = cvtpk(a1[0], a1[1]);
      au[3] = cvtpk(a1[2], a1[3]);
      int sb = (4 * kk + g) ^ (c & 7);
#pragma unroll
      for (int n = 0; n < 3; ++n) {
        int h = 48 * wc + 16 * n + c;
        s16x8 bf = *(const s16x8*)(bs + h * 64 + sb * 8);
        acc[n] = MFMA16(af, bf, acc[n]);
      }
    }
    __syncthreads();
  }
#undef STAGE

#pragma unroll
  for (int n = 0; n < 3; ++n) {
    int base = 48 * wc + 16 * n;  // 16-aligned, never straddles a 64-boundary
    int m = base >> 6;
    int h = (base + c) & 63;
#pragma unroll
    for (int r = 0; r < 4; ++r) {
      unsigned short hv = f2bf(acc[n][r]);
      int grow = row0 + 16 * wr + 4 * g + r;
      if (m == 0) qm[(size_t)grow * 64 + h] = hv;
      else if (m == 1) km[(size_t)grow * 64 + h] = hv;
      else vt[((size_t)b * 64 + h) * 4096 + (grow & 4095)] = hv;
    }
  }
}

// ---------- kernel 3: flash attention, swapped-QK^T 32x32 structure ----------
__global__ __launch_bounds__(512) void attn_kernel(const unsigned short* __restrict__ qm,
                                                   const unsigned short* __restrict__ km,
                                                   const unsigned short* __restrict__ vt,
                                                   float* __restrict__ out) {
  __shared__ float Olds[4][32][64];  // 32 KiB, used in 2 phases (waves 0-3, 4-7)
  __shared__ float mlds[8][32];
  __shared__ float llds[8][32];
  __shared__ float flds[8][32];

  int tid = threadIdx.x;
  int lane = tid & 63, wv = tid >> 6;
  int ln = lane & 31, hi = lane >> 5;
  int bid = blockIdx.x;
  int b = bid & 3;
  int j = 127 - (bid >> 2);  // big Q-tiles dispatched first
  int q0 = j * 32;
  const float SC = 0.1803368801111204f;  // (1/sqrt(64)) * log2(e)

  const unsigned short* qb = qm + ((size_t)b * 4096 + q0 + ln) * 64 + 8 * hi;
  s16x8 qf0 = *(const s16x8*)(qb);
  s16x8 qf1 = *(const s16x8*)(qb + 16);
  s16x8 qf2 = *(const s16x8*)(qb + 32);
  s16x8 qf3 = *(const s16x8*)(qb + 48);

  const unsigned short* kbb = km + (size_t)b * 4096 * 64 + (size_t)ln * 64 + 8 * hi;
  const unsigned short* vbb = vt + (size_t)b * 64 * 4096 + (size_t)ln * 4096 + 8 * hi;

  f32x16 of0 = {0.f, 0.f, 0.f, 0.f, 0.f, 0.f, 0.f, 0.f,
                0.f, 0.f, 0.f, 0.f, 0.f, 0.f, 0.f, 0.f};
  f32x16 of1 = of0;
  float mrow = -1e30f;
  float l = 0.f;

  auto process = [&](int kv0, bool diag) {
    const unsigned short* kp = kbb + (size_t)kv0 * 64;
    s16x8 kf0 = *(const s16x8*)(kp);
    s16x8 kf1 = *(const s16x8*)(kp + 16);
    s16x8 kf2 = *(const s16x8*)(kp + 32);
    s16x8 kf3 = *(const s16x8*)(kp + 48);
    f32x16 s = {0.f, 0.f, 0.f, 0.f, 0.f, 0.f, 0.f, 0.f,
                0.f, 0.f, 0.f, 0.f, 0.f, 0.f, 0.f, 0.f};
    __builtin_amdgcn_s_setprio(1);
    s = MFMA32(kf0, qf0, s);
    s = MFMA32(kf1, qf1, s);
    s = MFMA32(kf2, qf2, s);
    s = MFMA32(kf3, qf3, s);
    __builtin_amdgcn_s_setprio(0);

    float p[16];
#pragma unroll
    for (int r = 0; r < 16; ++r) p[r] = s[r] * SC;
    if (diag) {
#pragma unroll
      for (int r = 0; r < 16; ++r) {
        int kvr = (r & 3) + 8 * (r >> 2) + 4 * hi;
        if (kvr > ln) p[r] = -1e30f;
      }
    }
    float tmax = fmaxf(p[0], p[1]);
#pragma unroll
    for (int r = 2; r < 16; ++r) tmax = fmaxf(tmax, p[r]);
    tmax = fmaxf(tmax, __shfl_xor(tmax, 32));
    if (!__all(tmax <= mrow + 8.0f)) {
      float nm = fmaxf(mrow, tmax);
      float al = __builtin_amdgcn_exp2f(mrow - nm);
      mrow = nm;
      l *= al;
#pragma unroll
      for (int r = 0; r < 16; ++r) { of0[r] *= al; of1[r] *= al; }
    }
    float lp = 0.f;
#pragma unroll
    for (int r = 0; r < 16; ++r) {
      p[r] = __builtin_amdgcn_exp2f(p[r] - mrow);
      lp += p[r];
    }
    lp += __shfl_xor(lp, 32);
    l += lp;

    u32x4 w0, w1;
    {
      unsigned x0 = cvtpk(p[0], p[1]), y0 = cvtpk(p[4], p[5]);
      plswap(x0, y0);
      unsigned x1 = cvtpk(p[2], p[3]), y1 = cvtpk(p[6], p[7]);
      plswap(x1, y1);
      w0[0] = x0; w0[1] = x1; w0[2] = y0; w0[3] = y1;
      unsigned x2 = cvtpk(p[8], p[9]), y2 = cvtpk(p[12], p[13]);
      plswap(x2, y2);
      unsigned x3 = cvtpk(p[10], p[11]), y3 = cvtpk(p[14], p[15]);
      plswap(x3, y3);
      w1[0] = x2; w1[1] = x3; w1[2] = y2; w1[3] = y3;
    }
    s16x8 pa0 = __builtin_bit_cast(s16x8, w0);
    s16x8 pa1 = __builtin_bit_cast(s16x8, w1);

    const unsigned short* vp = vbb + kv0;
    s16x8 vf00 = *(const s16x8*)(vp);
    s16x8 vf01 = *(const s16x8*)(vp + 16);
    s16x8 vf10 = *(const s16x8*)(vp + 32 * 4096);
    s16x8 vf11 = *(const s16x8*)(vp + 32 * 4096 + 16);
    __builtin_amdgcn_s_setprio(1);
    of0 = MFMA32(pa0, vf00, of0);
    of0 = MFMA32(pa1, vf01, of0);
    of1 = MFMA32(pa0, vf10, of1);
    of1 = MFMA32(pa1, vf11, of1);
    __builtin_amdgcn_s_setprio(0);
  };

  for (int t = wv; t < j; t += 8) process(t * 32, false);
  if (wv == (j & 7)) process(q0, true);

  if (hi == 0) {
    mlds[wv][ln] = mrow;
    llds[wv][ln] = l;
  }
  __syncthreads();

  if (tid < 32) {
    int row = tid;
    float M = mlds[0][row];
#pragma unroll
    for (int w = 1; w < 8; ++w) M = fmaxf(M, mlds[w][row]);
    float L = 0.f, f[8];
#pragma unroll
    for (int w = 0; w < 8; ++w) {
      f[w] = __builtin_amdgcn_exp2f(mlds[w][row] - M);
      L += llds[w][row] * f[w];
    }
    float rL = 1.0f / L;
#pragma unroll
    for (int w = 0; w < 8; ++w) flds[w][row] = f[w] * rL;
  }

  if (wv < 4) {
#pragma unroll
    for (int r = 0; r < 16; ++r) {
      int qr = (r & 3) + 8 * (r >> 2) + 4 * hi;
      Olds[wv][qr][ln] = of0[r];
      Olds[wv][qr][32 + ln] = of1[r];
    }
  }
  __syncthreads();

  float accv[4];
#pragma unroll
  for (int ii = 0; ii < 4; ++ii) {
    int idx = ii * 512 + tid;
    int row = idx >> 6, d = idx & 63;
    float a = 0.f;
#pragma unroll
    for (int w = 0; w < 4; ++w) a += Olds[w][row][d] * flds[w][row];
    accv[ii] = a;
  }
  __syncthreads();

  if (wv >= 4) {
#pragma unroll
    for (int r = 0; r < 16; ++r) {
      int qr = (r & 3) + 8 * (r >> 2) + 4 * hi;
      Olds[wv - 4][qr][ln] = of0[r];
      Olds[wv - 4][qr][32 + ln] = of1[r];
    }
  }
  __syncthreads();

#pragma unroll
  for (int ii = 0; ii < 4; ++ii) {
    int idx = ii * 512 + tid;
    int row = idx >> 6, d = idx & 63;
    float a = accv[ii];
#pragma unroll
    for (int w = 0; w < 4; ++w) a += Olds[w][row][d] * flds[w + 4][row];
    out[((size_t)b * 4096 + q0 + row) * 64 + d] = a;
  }
}

extern "C" void kernel_launch(void* const* d_in, const int* in_sizes, int n_in,
                              void* d_out, int out_size, void* d_ws, size_t ws_size,
                              hipStream_t stream) {
  const float* x = (const float*)d_in[0];
  const float* Wq = (const float*)d_in[1];
  const float* Wk = (const float*)d_in[2];
  const float* Wv = (const float*)d_in[3];
  float* out = (float*)d_out;

  char* ws = (char*)d_ws;
  unsigned short* Wt = (unsigned short*)ws;                  // 384 KiB
  unsigned short* qm = (unsigned short*)(ws + 0x60000);      // 2 MiB
  unsigned short* km = qm + (size_t)16384 * 64;              // 2 MiB
  unsigned short* vt = km + (size_t)16384 * 64;              // [4][64][4096] bf16

  wt_kernel<<<dim3(48), dim3(256), 0, stream>>>(Wq, Wk, Wv, Wt);
  proj_kernel<<<dim3(512), dim3(512), 0, stream>>>(x, Wt, qm, km, vt);
  attn_kernel<<<dim3(512), dim3(512), 0, stream>>>(qm, km, vt, out);
}

// Round 7
// 47.510 us; speedup vs baseline: 2.3836x; 1.5939x over previous
//
#include <hip/hip_runtime.h>

typedef short s16x8 __attribute__((ext_vector_type(8)));
typedef float f32x4 __attribute__((ext_vector_type(4)));
typedef float f32x16 __attribute__((ext_vector_type(16)));
typedef unsigned int u32x4 __attribute__((ext_vector_type(4)));

#define MFMA16(a, b, c) __builtin_amdgcn_mfma_f32_16x16x32_bf16(a, b, c, 0, 0, 0)
#define MFMA32(a, b, c) __builtin_amdgcn_mfma_f32_32x32x16_bf16(a, b, c, 0, 0, 0)

__device__ __forceinline__ unsigned short f2bf(float f) {
  unsigned int u = __builtin_bit_cast(unsigned int, f);
  u += 0x7FFFu + ((u >> 16) & 1u);
  return (unsigned short)(u >> 16);
}

__device__ __forceinline__ unsigned cvtpk(float lo, float hi) {
  unsigned r;
  asm("v_cvt_pk_bf16_f32 %0, %1, %2" : "=v"(r) : "v"(lo), "v"(hi));
  return r;
}

// vdst' = (vdst.lo, vsrc.lo); vsrc' = (vdst.hi, vsrc.hi)
__device__ __forceinline__ void plswap(unsigned& a, unsigned& b) {
  asm("v_permlane32_swap_b32 %0, %1" : "+v"(a), "+v"(b));
}

// ---------- kernel 1: W [1024][64] fp32 -> Wt [3][64][1024] bf16 ----------
__global__ __launch_bounds__(256) void wt_kernel(const float* __restrict__ Wq,
                                                 const float* __restrict__ Wk,
                                                 const float* __restrict__ Wv,
                                                 unsigned short* __restrict__ Wt) {
  __shared__ float w[64][65];
  int blk = blockIdx.x;  // 48 = 3 matrices x 16 column-tiles
  int m = blk >> 4;
  int c0 = (blk & 15) * 64;
  const float* W = (m == 0) ? Wq : (m == 1) ? Wk : Wv;
  int tid = threadIdx.x;
#pragma unroll
  for (int k = 0; k < 4; ++k) {
    int id = tid + k * 256;  // 64 c-rows x 16 float4 chunks
    int crow = id >> 4, ch = id & 15;
    float4 v = *(const float4*)(W + (size_t)(c0 + crow) * 64 + ch * 4);
    w[crow][ch * 4 + 0] = v.x;
    w[crow][ch * 4 + 1] = v.y;
    w[crow][ch * 4 + 2] = v.z;
    w[crow][ch * 4 + 3] = v.w;
  }
  __syncthreads();
#pragma unroll
  for (int k = 0; k < 4; ++k) {
    int id = tid + k * 256;  // 64 h-rows x 16 4-col chunks
    int h = id >> 4, j = id & 15;
    ushort4 o;
    o.x = f2bf(w[4 * j + 0][h]);
    o.y = f2bf(w[4 * j + 1][h]);
    o.z = f2bf(w[4 * j + 2][h]);
    o.w = f2bf(w[4 * j + 3][h]);
    *(ushort4*)(Wt + (size_t)(m * 64 + h) * 1024 + c0 + 4 * j) = o;
  }
}

// ---------- kernel 2: projection GEMM (R5 structure) ----------
// Writes q row-major (pre-scaled by 1/sqrt(64)*log2e), K and V in MFMA
// FRAGMENT ORDER (kfl/vfl[b][t][slice][lane] 16B-contiguous) so attn's K/V
// loads are dense coalesced 1KB wave-reads (kills the 32-row scatter).
__global__ __launch_bounds__(512) void proj_kernel(const float* __restrict__ x,
                                                   const unsigned short* __restrict__ Wt,
                                                   unsigned short* __restrict__ qm,
                                                   unsigned short* __restrict__ kfl,
                                                   unsigned short* __restrict__ vfl) {
  __shared__ float xb[2][32 * 64];           // 2 x 8 KiB
  __shared__ unsigned short bb[2][192 * 64]; // 2 x 24 KiB

  int tid = threadIdx.x;
  int lane = tid & 63, wv = tid >> 6;
  int c = lane & 15, g = lane >> 4;
  int wr = wv & 1, wc = wv >> 1;
  int row0 = blockIdx.x * 32;
  int b = blockIdx.x >> 7;
  const float SCQ = 0.1803368801111204f;  // (1/sqrt(64)) * log2(e)

  const float* xsrc =
      x + (size_t)(row0 + (tid >> 4)) * 1024 + ((tid & 15) ^ ((tid >> 4) & 7)) * 4;
  const unsigned short* bsrc0;
  const unsigned short* bsrc1;
  const unsigned short* bsrc2;
  {
    int d0 = tid, d1 = tid + 512, d2 = tid + 1024;
    bsrc0 = Wt + (size_t)(d0 >> 3) * 1024 + ((d0 & 7) ^ ((d0 >> 3) & 7)) * 8;
    bsrc1 = Wt + (size_t)(d1 >> 3) * 1024 + ((d1 & 7) ^ ((d1 >> 3) & 7)) * 8;
    bsrc2 = Wt + (size_t)(d2 >> 3) * 1024 + ((d2 & 7) ^ ((d2 >> 3) & 7)) * 8;
  }

#define STAGE(buf, t)                                                                 \
  do {                                                                                \
    __builtin_amdgcn_global_load_lds(                                                 \
        (const __attribute__((address_space(1))) unsigned int*)(xsrc + (t) * 64),     \
        (__attribute__((address_space(3))) unsigned int*)(&xb[buf][wv * 256]), 16, 0, 0); \
    __builtin_amdgcn_global_load_lds(                                                 \
        (const __attribute__((address_space(1))) unsigned int*)(bsrc0 + (t) * 64),    \
        (__attribute__((address_space(3))) unsigned int*)(&bb[buf][wv * 512]), 16, 0, 0); \
    __builtin_amdgcn_global_load_lds(                                                 \
        (const __attribute__((address_space(1))) unsigned int*)(bsrc1 + (t) * 64),    \
        (__attribute__((address_space(3))) unsigned int*)(&bb[buf][wv * 512 + 4096]), 16, 0, 0); \
    __builtin_amdgcn_global_load_lds(                                                 \
        (const __attribute__((address_space(1))) unsigned int*)(bsrc2 + (t) * 64),    \
        (__attribute__((address_space(3))) unsigned int*)(&bb[buf][wv * 512 + 8192]), 16, 0, 0); \
  } while (0)

  f32x4 acc[3];
  acc[0] = (f32x4){0.f, 0.f, 0.f, 0.f};
  acc[1] = acc[0];
  acc[2] = acc[0];

  STAGE(0, 0);
  __syncthreads();

  int arow = 16 * wr + c;
  for (int t = 0; t < 16; ++t) {
    int buf = t & 1;
    if (t < 15) STAGE(buf ^ 1, t + 1);
    const float* xs = xb[buf];
    const unsigned short* bs = bb[buf];
#pragma unroll
    for (int kk = 0; kk < 2; ++kk) {
      int s0 = (8 * kk + 2 * g) ^ (c & 7);
      f32x4 a0 = *(const f32x4*)(xs + arow * 64 + s0 * 4);
      f32x4 a1 = *(const f32x4*)(xs + arow * 64 + (s0 ^ 1) * 4);
      s16x8 af;
      unsigned* au = (unsigned*)&af;
      au[0] = cvtpk(a0[0], a0[1]);
      au[1] = cvtpk(a0[2], a0[3]);
      au[2] = cvtpk(a1[0], a1[1]);
      au[3] = cvtpk(a1[2], a1[3]);
      int sb = (4 * kk + g) ^ (c & 7);
#pragma unroll
      for (int n = 0; n < 3; ++n) {
        int h = 48 * wc + 16 * n + c;
        s16x8 bf = *(const s16x8*)(bs + h * 64 + sb * 8);
        acc[n] = MFMA16(af, bf, acc[n]);
      }
    }
    __syncthreads();
  }
#undef STAGE

#pragma unroll
  for (int n = 0; n < 3; ++n) {
    int base = 48 * wc + 16 * n;  // 16-aligned
    int m = base >> 6;
    int h = (base + c) & 63;
#pragma unroll
    for (int r = 0; r < 4; ++r) {
      int grow = row0 + 16 * wr + 4 * g + r;
      float v = acc[n][r];
      if (m == 0) {
        qm[(size_t)grow * 64 + h] = f2bf(v * SCQ);
      } else if (m == 1) {
        // kfl: element K[grow][h] -> [b][t][ks][lane=32*hi+ln][j]
        int tloc = (grow >> 5) & 127;
        int ln2 = grow & 31;
        int ks = h >> 4, hi2 = (h >> 3) & 1, j = h & 7;
        kfl[(size_t)(b * 128 + tloc) * 2048 + ks * 512 + (hi2 * 32 + ln2) * 8 + j] = f2bf(v);
      } else {
        // vfl: element V[kv=grow][d=h] -> [b][t][sl][lane=32*hi+ln][j]
        int tloc = (grow >> 5) & 127;
        int sl = 2 * (h >> 5) + ((grow >> 4) & 1);
        int lane2 = ((grow >> 3) & 1) * 32 + (h & 31);
        int j = grow & 7;
        vfl[(size_t)(b * 128 + tloc) * 2048 + sl * 512 + lane2 * 8 + j] = f2bf(v);
      }
    }
  }
}

// ---------- kernel 3: flash attention, paired q-tiles + fragment K/V + prefetch --
// 256 blocks = (b in 0..3) x (jp in 0..63); block handles q-tiles jA=jp and
// jB=127-jp -> exactly ~129 kv-tiles per block: perfect balance, 1 block/CU.
// 8 waves split each q-tile's kv range strided by 8. K/V loads are dense
// fragment-order 1KB reads, prefetched 1 tile ahead into registers.
__global__ __launch_bounds__(512) void attn_kernel(const unsigned short* __restrict__ qm,
                                                   const unsigned short* __restrict__ kfl,
                                                   const unsigned short* __restrict__ vfl,
                                                   float* __restrict__ out) {
  __shared__ float Olds[8][32][64];  // 64 KiB
  __shared__ float mlds[2][8][32];
  __shared__ float llds[2][8][32];
  __shared__ float flds[2][8][32];

  int tid = threadIdx.x;
  int lane = tid & 63, wv = tid >> 6;
  int ln = lane & 31, hi = lane >> 5;
  int bid = blockIdx.x;
  int b = bid & 3;
  int jA = bid >> 2;        // 0..63
  int jB = 127 - jA;        // 64..127
  int q0A = jA * 32, q0B = jB * 32;

  // Q fragments (pre-scaled at proj time)
  const unsigned short* qa = qm + ((size_t)b * 4096 + q0A + ln) * 64 + 8 * hi;
  s16x8 qa0 = *(const s16x8*)(qa);
  s16x8 qa1 = *(const s16x8*)(qa + 16);
  s16x8 qa2 = *(const s16x8*)(qa + 32);
  s16x8 qa3 = *(const s16x8*)(qa + 48);
  const unsigned short* qb = qm + ((size_t)b * 4096 + q0B + ln) * 64 + 8 * hi;
  s16x8 qb0 = *(const s16x8*)(qb);
  s16x8 qb1 = *(const s16x8*)(qb + 16);
  s16x8 qb2 = *(const s16x8*)(qb + 32);
  s16x8 qb3 = *(const s16x8*)(qb + 48);

  const unsigned short* kb = kfl + (size_t)b * 128 * 2048 + lane * 8;
  const unsigned short* vb = vfl + (size_t)b * 128 * 2048 + lane * 8;

  f32x16 oA0 = {0.f, 0.f, 0.f, 0.f, 0.f, 0.f, 0.f, 0.f,
                0.f, 0.f, 0.f, 0.f, 0.f, 0.f, 0.f, 0.f};
  f32x16 oA1 = oA0, oB0 = oA0, oB1 = oA0;
  float mA = -1e30f, lA = 0.f, mB = -1e30f, lB = 0.f;

  auto tile = [&](const s16x8& kf0, const s16x8& kf1, const s16x8& kf2, const s16x8& kf3,
                  const s16x8& vf00, const s16x8& vf01, const s16x8& vf10, const s16x8& vf11,
                  const s16x8& qf0, const s16x8& qf1, const s16x8& qf2, const s16x8& qf3,
                  bool diag, f32x16& o0, f32x16& o1, float& mrow, float& l) {
    f32x16 s = {0.f, 0.f, 0.f, 0.f, 0.f, 0.f, 0.f, 0.f,
                0.f, 0.f, 0.f, 0.f, 0.f, 0.f, 0.f, 0.f};
    __builtin_amdgcn_s_setprio(1);
    s = MFMA32(kf0, qf0, s);
    s = MFMA32(kf1, qf1, s);
    s = MFMA32(kf2, qf2, s);
    s = MFMA32(kf3, qf3, s);
    __builtin_amdgcn_s_setprio(0);

    float p[16];
#pragma unroll
    for (int r = 0; r < 16; ++r) p[r] = s[r];
    if (diag) {
#pragma unroll
      for (int r = 0; r < 16; ++r) {
        int kvr = (r & 3) + 8 * (r >> 2) + 4 * hi;
        if (kvr > ln) p[r] = -1e30f;
      }
    }
    float tmax = fmaxf(p[0], p[1]);
#pragma unroll
    for (int r = 2; r < 16; ++r) tmax = fmaxf(tmax, p[r]);
    tmax = fmaxf(tmax, __shfl_xor(tmax, 32));
    if (!__all(tmax <= mrow + 8.0f)) {
      float nm = fmaxf(mrow, tmax);
      float al = __builtin_amdgcn_exp2f(mrow - nm);
      mrow = nm;
      l *= al;
#pragma unroll
      for (int r = 0; r < 16; ++r) { o0[r] *= al; o1[r] *= al; }
    }
    float lp = 0.f;
#pragma unroll
    for (int r = 0; r < 16; ++r) {
      p[r] = __builtin_amdgcn_exp2f(p[r] - mrow);
      lp += p[r];
    }
    lp += __shfl_xor(lp, 32);
    l += lp;

    u32x4 w0, w1;
    {
      unsigned x0 = cvtpk(p[0], p[1]), y0 = cvtpk(p[4], p[5]);
      plswap(x0, y0);
      unsigned x1 = cvtpk(p[2], p[3]), y1 = cvtpk(p[6], p[7]);
      plswap(x1, y1);
      w0[0] = x0; w0[1] = x1; w0[2] = y0; w0[3] = y1;
      unsigned x2 = cvtpk(p[8], p[9]), y2 = cvtpk(p[12], p[13]);
      plswap(x2, y2);
      unsigned x3 = cvtpk(p[10], p[11]), y3 = cvtpk(p[14], p[15]);
      plswap(x3, y3);
      w1[0] = x2; w1[1] = x3; w1[2] = y2; w1[3] = y3;
    }
    s16x8 pa0 = __builtin_bit_cast(s16x8, w0);
    s16x8 pa1 = __builtin_bit_cast(s16x8, w1);

    __builtin_amdgcn_s_setprio(1);
    o0 = MFMA32(pa0, vf00, o0);
    o0 = MFMA32(pa1, vf01, o0);
    o1 = MFMA32(pa0, vf10, o1);
    o1 = MFMA32(pa1, vf11, o1);
    __builtin_amdgcn_s_setprio(0);
  };

  // full (unmasked) tile lists, strided by 8 across waves
  int nA = (jA > wv) ? ((jA - wv + 7) >> 3) : 0;
  int nB = (jB > wv) ? ((jB - wv + 7) >> 3) : 0;
  int nt = nA + nB;

  // prefetch tile 0
  int t0 = (0 < nA) ? wv : wv;  // first tile kv index is wv in either list
  const unsigned short* kp = kb + t0 * 2048;
  const unsigned short* vp = vb + t0 * 2048;
  s16x8 kc0 = *(const s16x8*)(kp);
  s16x8 kc1 = *(const s16x8*)(kp + 512);
  s16x8 kc2 = *(const s16x8*)(kp + 1024);
  s16x8 kc3 = *(const s16x8*)(kp + 1536);
  s16x8 vc0 = *(const s16x8*)(vp);
  s16x8 vc1 = *(const s16x8*)(vp + 512);
  s16x8 vc2 = *(const s16x8*)(vp + 1024);
  s16x8 vc3 = *(const s16x8*)(vp + 1536);

  for (int i = 0; i < nt; ++i) {
    int inx = i + 1;
    int tn = (inx < nt) ? ((inx < nA) ? (wv + 8 * inx) : (wv + 8 * (inx - nA))) : 0;
    const unsigned short* kpn = kb + tn * 2048;
    const unsigned short* vpn = vb + tn * 2048;
    s16x8 kn0 = *(const s16x8*)(kpn);
    s16x8 kn1 = *(const s16x8*)(kpn + 512);
    s16x8 kn2 = *(const s16x8*)(kpn + 1024);
    s16x8 kn3 = *(const s16x8*)(kpn + 1536);
    s16x8 vn0 = *(const s16x8*)(vpn);
    s16x8 vn1 = *(const s16x8*)(vpn + 512);
    s16x8 vn2 = *(const s16x8*)(vpn + 1024);
    s16x8 vn3 = *(const s16x8*)(vpn + 1536);

    if (i < nA)
      tile(kc0, kc1, kc2, kc3, vc0, vc1, vc2, vc3, qa0, qa1, qa2, qa3, false, oA0, oA1, mA, lA);
    else
      tile(kc0, kc1, kc2, kc3, vc0, vc1, vc2, vc3, qb0, qb1, qb2, qb3, false, oB0, oB1, mB, lB);

    kc0 = kn0; kc1 = kn1; kc2 = kn2; kc3 = kn3;
    vc0 = vn0; vc1 = vn1; vc2 = vn2; vc3 = vn3;
  }

  // diagonal (masked) tiles — dense fragment loads, no prefetch needed
  if (wv == (jA & 7)) {
    const unsigned short* kpd = kb + jA * 2048;
    const unsigned short* vpd = vb + jA * 2048;
    s16x8 kd0 = *(const s16x8*)(kpd);
    s16x8 kd1 = *(const s16x8*)(kpd + 512);
    s16x8 kd2 = *(const s16x8*)(kpd + 1024);
    s16x8 kd3 = *(const s16x8*)(kpd + 1536);
    s16x8 vd0 = *(const s16x8*)(vpd);
    s16x8 vd1 = *(const s16x8*)(vpd + 512);
    s16x8 vd2 = *(const s16x8*)(vpd + 1024);
    s16x8 vd3 = *(const s16x8*)(vpd + 1536);
    tile(kd0, kd1, kd2, kd3, vd0, vd1, vd2, vd3, qa0, qa1, qa2, qa3, true, oA0, oA1, mA, lA);
  }
  if (wv == (jB & 7)) {
    const unsigned short* kpd = kb + jB * 2048;
    const unsigned short* vpd = vb + jB * 2048;
    s16x8 kd0 = *(const s16x8*)(kpd);
    s16x8 kd1 = *(const s16x8*)(kpd + 512);
    s16x8 kd2 = *(const s16x8*)(kpd + 1024);
    s16x8 kd3 = *(const s16x8*)(kpd + 1536);
    s16x8 vd0 = *(const s16x8*)(vpd);
    s16x8 vd1 = *(const s16x8*)(vpd + 512);
    s16x8 vd2 = *(const s16x8*)(vpd + 1024);
    s16x8 vd3 = *(const s16x8*)(vpd + 1536);
    tile(kd0, kd1, kd2, kd3, vd0, vd1, vd2, vd3, qb0, qb1, qb2, qb3, true, oB0, oB1, mB, lB);
  }

  // ---- merge: A then B through 64 KiB Olds ----
  if (hi == 0) {
    mlds[0][wv][ln] = mA;
    llds[0][wv][ln] = lA;
    mlds[1][wv][ln] = mB;
    llds[1][wv][ln] = lB;
  }
#pragma unroll
  for (int r = 0; r < 16; ++r) {
    int qr = (r & 3) + 8 * (r >> 2) + 4 * hi;
    Olds[wv][qr][ln] = oA0[r];
    Olds[wv][qr][32 + ln] = oA1[r];
  }
  __syncthreads();

  if (tid < 64) {
    int t01 = tid >> 5, row = tid & 31;
    float M = mlds[t01][0][row];
#pragma unroll
    for (int w = 1; w < 8; ++w) M = fmaxf(M, mlds[t01][w][row]);
    float L = 0.f, f[8];
#pragma unroll
    for (int w = 0; w < 8; ++w) {
      f[w] = __builtin_amdgcn_exp2f(mlds[t01][w][row] - M);
      L += llds[t01][w][row] * f[w];
    }
    float rL = 1.0f / L;
#pragma unroll
    for (int w = 0; w < 8; ++w) flds[t01][w][row] = f[w] * rL;
  }
  __syncthreads();

#pragma unroll
  for (int ii = 0; ii < 4; ++ii) {
    int idx = ii * 512 + tid;
    int row = idx >> 6, d = idx & 63;
    float a = 0.f;
#pragma unroll
    for (int w = 0; w < 8; ++w) a += Olds[w][row][d] * flds[0][w][row];
    out[((size_t)b * 4096 + q0A + row) * 64 + d] = a;
  }
  __syncthreads();

#pragma unroll
  for (int r = 0; r < 16; ++r) {
    int qr = (r & 3) + 8 * (r >> 2) + 4 * hi;
    Olds[wv][qr][ln] = oB0[r];
    Olds[wv][qr][32 + ln] = oB1[r];
  }
  __syncthreads();

#pragma unroll
  for (int ii = 0; ii < 4; ++ii) {
    int idx = ii * 512 + tid;
    int row = idx >> 6, d = idx & 63;
    float a = 0.f;
#pragma unroll
    for (int w = 0; w < 8; ++w) a += Olds[w][row][d] * flds[1][w][row];
    out[((size_t)b * 4096 + q0B + row) * 64 + d] = a;
  }
}

extern "C" void kernel_launch(void* const* d_in, const int* in_sizes, int n_in,
                              void* d_out, int out_size, void* d_ws, size_t ws_size,
                              hipStream_t stream) {
  const float* x = (const float*)d_in[0];
  const float* Wq = (const float*)d_in[1];
  const float* Wk = (const float*)d_in[2];
  const float* Wv = (const float*)d_in[3];
  float* out = (float*)d_out;

  char* ws = (char*)d_ws;
  unsigned short* Wt = (unsigned short*)ws;                  // 384 KiB
  unsigned short* qm = (unsigned short*)(ws + 0x60000);      // 2 MiB
  unsigned short* kfl = qm + (size_t)16384 * 64;             // 2 MiB (fragment order)
  unsigned short* vfl = kfl + (size_t)16384 * 64;            // 2 MiB (fragment order)

  wt_kernel<<<dim3(48), dim3(256), 0, stream>>>(Wq, Wk, Wv, Wt);
  proj_kernel<<<dim3(512), dim3(512), 0, stream>>>(x, Wt, qm, kfl, vfl);
  attn_kernel<<<dim3(256), dim3(512), 0, stream>>>(qm, kfl, vfl, out);
}